// Round 3
// baseline (212.679 us; speedup 1.0000x reference)
//
#include <hip/hip_runtime.h>
#include <cfloat>

typedef __attribute__((ext_vector_type(8))) short short8;
typedef __attribute__((ext_vector_type(4))) float f32x4;

#define NE 1024
#define EDIM 256
#define HW 1024
#define BSTRIDE (EDIM * HW)        // 262144
#define TOTAL 8388608

// workspace layout (bytes)
#define EMBB_OFF  0                        // ushort[1024*256] bf16 = 512 KB
#define ENORM_OFF (512 * 1024)             // float[1024]
#define HIST_OFF  (ENORM_OFF + 4096)       // int[1024]
#define LOSS_OFF  (HIST_OFF + 4096)        // float accumulator
#define DONE_OFF  (LOSS_OFF + 16)          // int completion counter

// round-to-nearest-even fp32 -> bf16 bits (inputs are finite)
__device__ __forceinline__ unsigned short f2bf(float x) {
    unsigned u = __builtin_bit_cast(unsigned, x);
    return (unsigned short)((u + 0x7fffu + ((u >> 16) & 1u)) >> 16);
}

// ---------------------------------------------------------------------------
// P: emb fp32 [1024][256] -> embB bf16 rows + enorm. 64 blocks x 256 thr,
// 16 threads per code row. Block 0 also zeroes hist/loss/done.
// ---------------------------------------------------------------------------
__global__ void prep_emb(const float* __restrict__ emb,
                         unsigned short* __restrict__ embB,
                         float* __restrict__ enorm,
                         int* __restrict__ hist,
                         float* __restrict__ lossAcc,
                         int* __restrict__ done) {
    int t = threadIdx.x;
    int gid = blockIdx.x * 256 + t;        // 0..16383
    int row = gid >> 4, seg = gid & 15;
    const float4* e4 = (const float4*)(emb + (size_t)row * EDIM) + seg * 4;
    float4 a0 = e4[0], a1 = e4[1], a2 = e4[2], a3 = e4[3];
    float s = a0.x * a0.x + a0.y * a0.y + a0.z * a0.z + a0.w * a0.w
            + a1.x * a1.x + a1.y * a1.y + a1.z * a1.z + a1.w * a1.w
            + a2.x * a2.x + a2.y * a2.y + a2.z * a2.z + a2.w * a2.w
            + a3.x * a3.x + a3.y * a3.y + a3.z * a3.z + a3.w * a3.w;
    short8 v0, v1;
    v0[0] = (short)f2bf(a0.x); v0[1] = (short)f2bf(a0.y);
    v0[2] = (short)f2bf(a0.z); v0[3] = (short)f2bf(a0.w);
    v0[4] = (short)f2bf(a1.x); v0[5] = (short)f2bf(a1.y);
    v0[6] = (short)f2bf(a1.z); v0[7] = (short)f2bf(a1.w);
    v1[0] = (short)f2bf(a2.x); v1[1] = (short)f2bf(a2.y);
    v1[2] = (short)f2bf(a2.z); v1[3] = (short)f2bf(a2.w);
    v1[4] = (short)f2bf(a3.x); v1[5] = (short)f2bf(a3.y);
    v1[6] = (short)f2bf(a3.z); v1[7] = (short)f2bf(a3.w);
    *(short8*)&embB[(size_t)row * EDIM + seg * 16]     = v0;
    *(short8*)&embB[(size_t)row * EDIM + seg * 16 + 8] = v1;
    s += __shfl_xor(s, 1, 64);
    s += __shfl_xor(s, 2, 64);
    s += __shfl_xor(s, 4, 64);
    s += __shfl_xor(s, 8, 64);
    if (seg == 0) enorm[row] = s;
    if (blockIdx.x == 0) {                 // fold memset into this dispatch
        ((int4*)hist)[t] = (int4){0, 0, 0, 0};
        if (t == 0) { lossAcc[0] = 0.f; done[0] = 0; }
    }
}

// ---------------------------------------------------------------------------
// F: fused argmin + gather + loss + hist (+ last-block finalize).
// Block = 32 positions, 256 threads (4 waves), grid 1024 -> 4 blocks/CU
// resident, 16 waves/CU (50% occ; rounds 0-2 were capped at 19-25% by the
// 75 KB LDS union + grid 512 -> every pipe <10% busy, pure latency chain).
// LDS is now only As (32x264 bf16, 16.9 KB) + Ens + reduce scratch ~22 KB.
// Wave nw in 0..3 owns all 32 positions (2 m-frags in regs) x 256 codes,
// B fragments read directly from L2-resident embB (no staging barriers).
// Epilogue: direct float4 emb-row gather + float4 z re-read (L2-hot) +
// float4 z_q store along the position axis. No Es transpose buffer.
// Finalize folded in via device-scope done-counter; hist/loss read back
// with atomicAdd(p,0) so reads hit the coherent point (XCD-safe).
// ---------------------------------------------------------------------------
__global__ __launch_bounds__(256, 4) void fused_kernel(
        const float* __restrict__ z, const float* __restrict__ emb,
        const unsigned short* __restrict__ embB, const float* __restrict__ enormG,
        float* __restrict__ zq, int* __restrict__ hist,
        float* __restrict__ lossAcc, int* __restrict__ done,
        float* __restrict__ out) {
    __shared__ __align__(16) unsigned short As[32 * 264];   // 16.9 KB
    __shared__ float Ens[NE];
    __shared__ float rv[4][32];
    __shared__ int   ri[4][32];
    __shared__ int   idxm[32];
    __shared__ int   amLast;
    __shared__ float wsum[4];

    int t = threadIdx.x;                   // 0..255
    int m0 = blockIdx.x * 32;
    int b = m0 >> 10, pb = m0 & 1023;
    const float* zb  = z  + (size_t)b * BSTRIDE + pb;
    float*       zqb = zq + (size_t)b * BSTRIDE + pb;

    for (int j = t; j < NE; j += 256) Ens[j] = enormG[j];

    int pq = t & 7, cg = t >> 3;           // pq: position quad, cg: 8-ch group
    {   // stage A: 8 independent float4 loads along p, packed short8 writes
        const float* zp = zb + pq * 4;
        float4 zv[8];
#pragma unroll
        for (int v = 0; v < 8; ++v)
            zv[v] = *(const float4*)&zp[(size_t)(cg * 8 + v) * HW];
#pragma unroll
        for (int j = 0; j < 4; ++j) {
            short8 w8;
#pragma unroll
            for (int v = 0; v < 8; ++v) {
                float x = (j == 0) ? zv[v].x : (j == 1) ? zv[v].y
                        : (j == 2) ? zv[v].z : zv[v].w;
                w8[v] = (short)f2bf(x);
            }
            *(short8*)&As[(pq * 4 + j) * 264 + cg * 8] = w8;
        }
    }
    __syncthreads();

    int w = t >> 6, l = t & 63, lm = l & 15, q = l >> 4;
    int nw = w;                            // each wave: 256-code quarter

    short8 A[2][8];
#pragma unroll
    for (int s = 0; s < 2; ++s)
#pragma unroll
        for (int ks = 0; ks < 8; ++ks)
            A[s][ks] = *(const short8*)&As[(s * 16 + lm) * 264 + ks * 32 + q * 8];

    float bd[8]; int bi[8];
#pragma unroll
    for (int i = 0; i < 8; ++i) { bd[i] = FLT_MAX; bi[i] = 0x7fffffff; }

    // main loop: 16 col-frags of 16 codes, B direct from L2, no barriers.
    const short8* eB8 = (const short8*)embB;
#pragma unroll 2
    for (int ct = 0; ct < 16; ++ct) {
        int code = nw * 256 + ct * 16 + lm;
        const short8* bp = eB8 + (size_t)code * 32 + q;
        f32x4 a0a = {0,0,0,0}, a0b = {0,0,0,0};
        f32x4 a1a = {0,0,0,0}, a1b = {0,0,0,0};
#pragma unroll
        for (int ks = 0; ks < 8; ks += 2) {
            short8 Bv0 = bp[ks * 4];
            short8 Bv1 = bp[ks * 4 + 4];
            a0a = __builtin_amdgcn_mfma_f32_16x16x32_bf16(A[0][ks],     Bv0, a0a, 0, 0, 0);
            a1a = __builtin_amdgcn_mfma_f32_16x16x32_bf16(A[1][ks],     Bv0, a1a, 0, 0, 0);
            a0b = __builtin_amdgcn_mfma_f32_16x16x32_bf16(A[0][ks + 1], Bv1, a0b, 0, 0, 0);
            a1b = __builtin_amdgcn_mfma_f32_16x16x32_bf16(A[1][ks + 1], Bv1, a1b, 0, 0, 0);
        }
        float en = Ens[code];
#pragma unroll
        for (int r = 0; r < 4; ++r) {
            float d0 = en - 2.f * (a0a[r] + a0b[r]);
            if (d0 < bd[r])     { bd[r] = d0;     bi[r] = code; }
            float d1 = en - 2.f * (a1a[r] + a1b[r]);
            if (d1 < bd[4 + r]) { bd[4 + r] = d1; bi[4 + r] = code; }
        }
    }

    // reduce across the 16 code-columns (lanes sharing q)
#pragma unroll
    for (int off = 1; off < 16; off <<= 1) {
#pragma unroll
        for (int i = 0; i < 8; ++i) {
            float od = __shfl_xor(bd[i], off, 64);
            int   oi = __shfl_xor(bi[i], off, 64);
            if (od < bd[i] || (od == bd[i] && oi < bi[i])) { bd[i] = od; bi[i] = oi; }
        }
    }
    if (lm == 0) {
#pragma unroll
        for (int s = 0; s < 2; ++s)
#pragma unroll
            for (int r = 0; r < 4; ++r) {
                int p = s * 16 + q * 4 + r;
                rv[nw][p] = bd[s * 4 + r];
                ri[nw][p] = bi[s * 4 + r];
            }
    }
    __syncthreads();
    if (t < 32) {
        float v = rv[0][t]; int bix = ri[0][t];
#pragma unroll
        for (int j = 1; j < 4; ++j) {
            float vj = rv[j][t]; int ij = ri[j][t];
            if (vj < v || (vj == v && ij < bix)) { v = vj; bix = ij; }
        }
        idxm[t] = bix;
        atomicAdd(&hist[bix], 1);
    }
    __syncthreads();

    {   // epilogue: gather 4 emb rows (8 ch each), re-read z, write z_q, loss
        int p0 = pq * 4;
        float e0[8], e1[8], e2[8], e3[8];
        {
            const float4* a = (const float4*)(emb + (size_t)idxm[p0 + 0] * EDIM) + cg * 2;
            *(float4*)&e0[0] = a[0]; *(float4*)&e0[4] = a[1];
        }
        {
            const float4* a = (const float4*)(emb + (size_t)idxm[p0 + 1] * EDIM) + cg * 2;
            *(float4*)&e1[0] = a[0]; *(float4*)&e1[4] = a[1];
        }
        {
            const float4* a = (const float4*)(emb + (size_t)idxm[p0 + 2] * EDIM) + cg * 2;
            *(float4*)&e2[0] = a[0]; *(float4*)&e2[4] = a[1];
        }
        {
            const float4* a = (const float4*)(emb + (size_t)idxm[p0 + 3] * EDIM) + cg * 2;
            *(float4*)&e3[0] = a[0]; *(float4*)&e3[4] = a[1];
        }
        float zr[32];
#pragma unroll
        for (int v = 0; v < 8; ++v)
            *(float4*)&zr[v * 4] = *(const float4*)&zb[(size_t)(cg * 8 + v) * HW + p0];
        float ls = 0.f;
#pragma unroll
        for (int v = 0; v < 8; ++v) {
            int c = cg * 8 + v;
            float4 qv; qv.x = e0[v]; qv.y = e1[v]; qv.z = e2[v]; qv.w = e3[v];
            *(float4*)&zqb[(size_t)c * HW + p0] = qv;
            float dx = qv.x - zr[v * 4 + 0], dy = qv.y - zr[v * 4 + 1];
            float dz = qv.z - zr[v * 4 + 2], dw = qv.w - zr[v * 4 + 3];
            ls += dx * dx + dy * dy + dz * dz + dw * dw;
        }
#pragma unroll
        for (int off = 32; off; off >>= 1) ls += __shfl_down(ls, off, 64);
        if ((t & 63) == 0) atomicAdd(lossAcc, ls);
    }

    // last-block finalize (replaces the finalize dispatch)
    if (t == 0) {
        __threadfence();
        amLast = (atomicAdd(done, 1) == (int)gridDim.x - 1);
    }
    __syncthreads();
    if (amLast) {
        float s = 0.f;
        for (int j = t; j < NE; j += 256) {
            float p = (float)atomicAdd(&hist[j], 0) * (1.0f / 32768.0f);
            s += p * logf(p + 1e-10f);
        }
#pragma unroll
        for (int off = 32; off; off >>= 1) s += __shfl_down(s, off, 64);
        if ((t & 63) == 0) wsum[t >> 6] = s;
        __syncthreads();
        if (t == 0) {
            float S = wsum[0] + wsum[1] + wsum[2] + wsum[3];
            out[TOTAL]     = 1.25f * atomicAdd(lossAcc, 0.f) / (float)TOTAL;
            out[TOTAL + 1] = expf(-S);
        }
    }
}

extern "C" void kernel_launch(void* const* d_in, const int* in_sizes, int n_in,
                              void* d_out, int out_size, void* d_ws, size_t ws_size,
                              hipStream_t stream) {
    (void)in_sizes; (void)n_in; (void)out_size; (void)ws_size;
    const float* z   = (const float*)d_in[0];
    const float* emb = (const float*)d_in[1];
    float* out = (float*)d_out;
    char* ws = (char*)d_ws;
    unsigned short* embB = (unsigned short*)(ws + EMBB_OFF);
    float* enorm   = (float*)(ws + ENORM_OFF);
    int*   hist    = (int*)(ws + HIST_OFF);
    float* lossAcc = (float*)(ws + LOSS_OFF);
    int*   done    = (int*)(ws + DONE_OFF);

    prep_emb<<<64, 256, 0, stream>>>(emb, embB, enorm, hist, lossAcc, done);
    fused_kernel<<<1024, 256, 0, stream>>>(z, emb, embB, enorm, out, hist,
                                           lossAcc, done, out);
}